// Round 29
// baseline (50.114 us; speedup 1.0000x reference)
//
#include <hip/hip_runtime.h>
#include <hip/hip_bf16.h>

#define B_ 8
#define T_ 2048
#define D_ 128

typedef __attribute__((ext_vector_type(8))) short short8;
typedef __attribute__((ext_vector_type(4))) float f32x4;

static __device__ __forceinline__ short f2bf(float f) {
  __hip_bfloat16 h = __float2bfloat16(f);
  return *reinterpret_cast<short*>(&h);
}

// scale * log2(e):  (1/sqrt(128)) * 1.4426950408889634
#define SL 0.12754434770570355f

// q-supertile = 128 rows (8 waves x 16). ns(qt) = ceil((qt+1)/2) splits,
// balanced over 4qt+4 KV-tiles (6-8 tiles per block). UPB = sum ns = 72.
// Per-batch partials = 72 x 32 KB = 2.3 MB < 4 MB XCD L2 (R24 lesson).
#define UPB 72

// cumulative blocks before supertile i (ns: 1,1,2,2,3,3,...):
static __device__ __forceinline__ int base16(int i) {
  int m = i >> 1;
  return (i & 1) ? (m + 1) * (m + 1) : m * m + m;
}

// direct global->LDS, 16B per lane (dest = wave-uniform base + lane*16)
static __device__ __forceinline__ void gl_lds16(const void* g, void* l) {
  __builtin_amdgcn_global_load_lds(
      (const __attribute__((address_space(1))) unsigned*)g,
      (__attribute__((address_space(3))) unsigned*)l, 16, 0, 0);
}

// ---------------------------------------------------------------------------
// Kernel 1: projections with FUSED W-transpose. W^T staged per block into
// padded LDS (coalesced f32 pairs -> cvt_pk -> b32 stores). The kp output
// (attn's Q' operand) is PRE-SCALED by SL so attn's softmax is exp2f(sc)
// with no multiply. q,k row-major bf16; v TRANSPOSED [B][D][T].
__global__ __launch_bounds__(256) void proj_kernel(const float* __restrict__ x,
    const float* __restrict__ Wq, const float* __restrict__ Wk,
    const float* __restrict__ Wv,
    __hip_bfloat16* __restrict__ qp, __hip_bfloat16* __restrict__ kp,
    __hip_bfloat16* __restrict__ vpT) {
  const int wv = threadIdx.x >> 6, lane = threadIdx.x & 63;
  const int ar = lane & 15, kg = lane >> 4;
  const int row0 = blockIdx.x * 64 + wv * 16;
  const int b = row0 >> 11, tloc = row0 & 2047;
  const int m = blockIdx.y;

  __shared__ short WTl[128][132];   // W^T[n][k] bf16, +4 pad

  const float* W = (m == 0) ? Wq : (m == 1) ? Wk : Wv;
  // stage W^T: 32 iters, each thread covers (nn, k=2kp..2kp+1), coalesced in nn
#pragma unroll
  for (int it = 0; it < 32; ++it) {
    int idx = it * 256 + threadIdx.x;
    int kp2 = idx >> 7, nn = idx & 127;
    float f0 = W[(2 * kp2) * 128 + nn];
    float f1 = W[(2 * kp2 + 1) * 128 + nn];
    unsigned w;
    asm("v_cvt_pk_bf16_f32 %0, %1, %2" : "=v"(w) : "v"(f0), "v"(f1));
    *(unsigned*)&WTl[nn][2 * kp2] = w;
  }

  short8 a[4];
  {
    const float* px = x + (size_t)(row0 + ar) * 128 + kg * 8;
#pragma unroll
    for (int ks = 0; ks < 4; ++ks) {
      const float* p = px + ks * 32;
      f32x4 x0 = *(const f32x4*)p;
      f32x4 x1 = *(const f32x4*)(p + 4);
      short8 t;
      t[0] = f2bf(x0[0]); t[1] = f2bf(x0[1]); t[2] = f2bf(x0[2]); t[3] = f2bf(x0[3]);
      t[4] = f2bf(x1[0]); t[5] = f2bf(x1[1]); t[6] = f2bf(x1[2]); t[7] = f2bf(x1[3]);
      a[ks] = t;
    }
  }
  __syncthreads();   // W^T staged

  if (m < 2) {
    __hip_bfloat16* outp = (m == 0) ? qp : kp;
    const float osc = (m == 1) ? SL : 1.0f;   // fold softmax scale into kp
#pragma unroll
    for (int nt = 0; nt < 8; ++nt) {
      f32x4 acc = {0.f, 0.f, 0.f, 0.f};
#pragma unroll
      for (int ks = 0; ks < 4; ++ks) {
        short8 bfr = *(const short8*)&WTl[nt * 16 + ar][ks * 32 + kg * 8];
        acc = __builtin_amdgcn_mfma_f32_16x16x32_bf16(a[ks], bfr, acc, 0, 0, 0);
      }
#pragma unroll
      for (int r = 0; r < 4; ++r)
        outp[(size_t)(row0 + kg * 4 + r) * 128 + nt * 16 + ar] = __float2bfloat16(acc[r] * osc);
    }
  } else {
#pragma unroll
    for (int nt = 0; nt < 8; ++nt) {
      f32x4 acc = {0.f, 0.f, 0.f, 0.f};
#pragma unroll
      for (int ks = 0; ks < 4; ++ks) {
        short8 wfr = *(const short8*)&WTl[nt * 16 + ar][ks * 32 + kg * 8];
        acc = __builtin_amdgcn_mfma_f32_16x16x32_bf16(wfr, a[ks], acc, 0, 0, 0);
      }
#pragma unroll
      for (int r = 0; r < 4; ++r)
        vpT[((size_t)b * 128 + nt * 16 + kg * 4 + r) * 2048 + tloc + ar] = __float2bfloat16(acc[r]);
    }
  }
}

// ---------------------------------------------------------------------------
// Kernel 2: causal flash attention (roles swapped: Q'=k_proj(pre-scaled),
// K'=q_proj). 8 waves share one 128-row Q-tile; K/V staged once per block
// into a 4-deep LDS ring via global_load_lds. Prefetch depth 3: tile i+3
// issued AFTER barrier(i) (slot (i-1)&3 provably free there); counted-vmcnt
// waits unchanged. Fixed-m softmax: P = exp2f(sc) (SL folded into kp).
__global__ __launch_bounds__(512, 4) void attn_kernel(const __hip_bfloat16* __restrict__ qp,
    const __hip_bfloat16* __restrict__ kp, const __hip_bfloat16* __restrict__ vpT,
    float* __restrict__ out, __hip_bfloat16* __restrict__ po, float* __restrict__ pml,
    int chunked) {
  const int bid = blockIdx.x;
  const int b = bid & 7;            // batch -> XCD pinning
  const int u = bid >> 3;
  int qt, s, ns;
  if (chunked) {
    int g = 0;
#pragma unroll
    for (int i = 1; i < 16; ++i)
      if (u >= base16(i)) g = i;
    qt = g; s = u - base16(g); ns = (g + 2) >> 1;
  } else {
    qt = u; s = 0; ns = 1;
  }
  const int wv = threadIdx.x >> 6, lane = threadIdx.x & 63;
  const int ar = lane & 15, kg = lane >> 4;

  // KV ring: 4 slots x [frag(16)][lane(64) x 16B]; frags 0-7 = K, 8-15 = V
  __shared__ short KV[4][8192];
  __shared__ short Pl[8][16][52];   // [wave][q(16)][kv(32)+pad]
  short (*Plw)[52] = Pl[wv];

  const int qrow0 = qt * 128 + wv * 16;
  const size_t boff = (size_t)b * T_ * 128;
  const size_t bvoff = (size_t)b * 128 * 2048;

  short8 qf[4];
  {
    const __hip_bfloat16* qb = kp + boff + (size_t)(qrow0 + ar) * 128 + kg * 8;
#pragma unroll
    for (int ks = 0; ks < 4; ++ks) qf[ks] = *(const short8*)(qb + ks * 32);
  }

  f32x4 o[8];
  {
    f32x4 z = {0.f, 0.f, 0.f, 0.f};
#pragma unroll
    for (int i = 0; i < 8; ++i) o[i] = z;
  }
  float lpart = 0.f;   // per-lane: sum of P over this lane's kv set, q = ar

  // balanced KV-tile range over ntile = 4qt+4 tiles
  const int ntile = 4 * qt + 4;
  const int t0 = chunked ? (s * ntile) / ns : 0;
  const int t1 = chunked ? ((s + 1) * ntile) / ns : ntile;
  const int n = t1 - t0;

  // staging sources for this wave (frag fK = wv, frag fV = 8 + wv)
  const __hip_bfloat16* Ksrc0 = qp + boff + (size_t)((wv >> 2) * 16 + ar) * 128 + (wv & 3) * 32 + kg * 8;
  const __hip_bfloat16* Vsrc0 = vpT + bvoff + (size_t)(wv * 16 + ar) * 2048 + kg * 8;

  // prologue: stage tiles t0..t0+2 into ring slots 0..2 (depth-3 pipeline)
  gl_lds16(Ksrc0 + (size_t)t0 * 4096, &KV[0][wv * 512]);
  gl_lds16(Vsrc0 + (size_t)t0 * 32, &KV[0][(8 + wv) * 512]);
  if (n > 1) {
    gl_lds16(Ksrc0 + (size_t)(t0 + 1) * 4096, &KV[1][wv * 512]);
    gl_lds16(Vsrc0 + (size_t)(t0 + 1) * 32, &KV[1][(8 + wv) * 512]);
  }
  if (n > 2) {
    gl_lds16(Ksrc0 + (size_t)(t0 + 2) * 4096, &KV[2][wv * 512]);
    gl_lds16(Vsrc0 + (size_t)(t0 + 2) * 32, &KV[2][(8 + wv) * 512]);
  }

  for (int i = 0; i < n; ++i) {
    const int t = t0 + i;
    // counted wait: drain tile i's 2 loads; leave i+1/i+2 (if existing)
    const int rem = n - 1 - i;
    if (rem >= 2)      asm volatile("s_waitcnt vmcnt(4)" ::: "memory");
    else if (rem == 1) asm volatile("s_waitcnt vmcnt(2)" ::: "memory");
    else               asm volatile("s_waitcnt vmcnt(0)" ::: "memory");
    __builtin_amdgcn_s_barrier();   // all waves: tile i visible, compute(i-1) done
    asm volatile("" ::: "memory");

    if (i + 3 < n) {   // prefetch tile i+3 into slot (i+3)&3 = (i-1)&3 (free)
      gl_lds16(Ksrc0 + (size_t)(t + 3) * 4096, &KV[(i + 3) & 3][wv * 512]);
      gl_lds16(Vsrc0 + (size_t)(t + 3) * 32, &KV[(i + 3) & 3][(8 + wv) * 512]);
    }

    const short* buf = KV[i & 3];
    const int rel = qrow0 - t * 32;   // wave-uniform; >=31 -> no mask fires

    // --- QK: S^T = K Q'^T; lane(kg,ar) reg r = S^T[kv=nt*16+kg*4+r][q=ar]
    f32x4 sc[2];
#pragma unroll
    for (int nt = 0; nt < 2; ++nt) {
      f32x4 acc = {0.f, 0.f, 0.f, 0.f};
#pragma unroll
      for (int ks = 0; ks < 4; ++ks) {
        short8 kf = *(const short8*)&buf[(nt * 4 + ks) * 512 + lane * 8];
        acc = __builtin_amdgcn_mfma_f32_16x16x32_bf16(kf, qf[ks], acc, 0, 0, 0);
      }
      sc[nt] = acc;
    }

    // --- P = exp2f(sc) (SL pre-folded); pack 4 bf16 -> one b64 LDS store ---
    if (rel >= 31) {
#pragma unroll
      for (int nt = 0; nt < 2; ++nt) {
        float p0 = exp2f(sc[nt][0]), p1 = exp2f(sc[nt][1]);
        float p2 = exp2f(sc[nt][2]), p3 = exp2f(sc[nt][3]);
        lpart += (p0 + p1) + (p2 + p3);
        unsigned w0, w1;
        asm("v_cvt_pk_bf16_f32 %0, %1, %2" : "=v"(w0) : "v"(p0), "v"(p1));
        asm("v_cvt_pk_bf16_f32 %0, %1, %2" : "=v"(w1) : "v"(p2), "v"(p3));
        *(unsigned long long*)&Plw[ar][nt * 16 + kg * 4] =
            ((unsigned long long)w1 << 32) | (unsigned long long)w0;
      }
    } else {
#pragma unroll
      for (int nt = 0; nt < 2; ++nt) {
        float p[4];
#pragma unroll
        for (int r = 0; r < 4; ++r) {
          float v = sc[nt][r];
          if (nt * 16 + kg * 4 + r - rel > ar) v = -3.0e38f;   // kv > q
          p[r] = exp2f(v);
          lpart += p[r];
        }
        unsigned w0, w1;
        asm("v_cvt_pk_bf16_f32 %0, %1, %2" : "=v"(w0) : "v"(p[0]), "v"(p[1]));
        asm("v_cvt_pk_bf16_f32 %0, %1, %2" : "=v"(w1) : "v"(p[2]), "v"(p[3]));
        *(unsigned long long*)&Plw[ar][nt * 16 + kg * 4] =
            ((unsigned long long)w1 << 32) | (unsigned long long)w0;
      }
    }

    // --- PV: O += P @ V (A = P rows from LDS, B = V^T frags) ---
    short8 pa = *(const short8*)&Plw[ar][kg * 8];
#pragma unroll
    for (int n8 = 0; n8 < 8; ++n8) {
      short8 vf = *(const short8*)&buf[(8 + n8) * 512 + lane * 8];
      o[n8] = __builtin_amdgcn_mfma_f32_16x16x32_bf16(pa, vf, o[n8], 0, 0, 0);
    }
  }

  // epilogue: l[q=ar] = sum over the 4 kg-groups; then fetch l for q=kg*4+r
  lpart += __shfl_xor(lpart, 16);
  lpart += __shfl_xor(lpart, 32);
  float lq[4];
#pragma unroll
  for (int r = 0; r < 4; ++r)
    lq[r] = __shfl(lpart, kg * 4 + r);

  if (ns == 1) {
#pragma unroll
    for (int r = 0; r < 4; ++r) lq[r] = 1.f / lq[r];
#pragma unroll
    for (int n8 = 0; n8 < 8; ++n8)
#pragma unroll
      for (int r = 0; r < 4; ++r)
        out[boff + (size_t)(qrow0 + kg * 4 + r) * 128 + n8 * 16 + ar] = o[n8][r] * lq[r];
  } else {
    // partial write (unnormalized bf16 o + f32 l)
    const int slot = b * UPB + u;
    __hip_bfloat16* pb = po + (size_t)slot * 128 * 128;
#pragma unroll
    for (int n8 = 0; n8 < 8; ++n8)
#pragma unroll
      for (int r = 0; r < 4; ++r)
        pb[(wv * 16 + kg * 4 + r) * 128 + n8 * 16 + ar] = __float2bfloat16(o[n8][r]);
    if (ar == 0) {
#pragma unroll
      for (int r = 0; r < 4; ++r)
        pml[slot * 128 + wv * 16 + kg * 4 + r] = lq[r];
    }
  }
}

// ---------------------------------------------------------------------------
// Kernel 3: merge splits for supertiles with ns>=2 (qt>=2: rows 256..2047).
// Vectorized: each thread handles 8 floats (one 16B bf16 load per split).
// thread = (b, row, 8-elem d chunk); grid = 8*1792*16/256 = 896 blocks.
__global__ __launch_bounds__(256) void combine_kernel(const __hip_bfloat16* __restrict__ po,
    const float* __restrict__ pml, float* __restrict__ out) {
  const int g0 = blockIdx.x * 256 + threadIdx.x;
  const int c = g0 & 15;                 // 8-float chunk index
  const int rowm = (g0 >> 4) % 1792;
  const int b = g0 / (1792 * 16);
  const int row = 256 + rowm;
  const int qt = row >> 7;
  const int ns = (qt + 2) >> 1;
  const int rowin = row & 127;
  const int slot0 = b * UPB + base16(qt);

  f32x4 num0 = {0.f, 0.f, 0.f, 0.f};
  f32x4 num1 = {0.f, 0.f, 0.f, 0.f};
  float den = 0.f;
  for (int s = 0; s < ns; ++s) {
    den += pml[(slot0 + s) * 128 + rowin];
    short8 ov = *(const short8*)(po + (size_t)(slot0 + s) * 128 * 128 + rowin * 128 + c * 8);
#pragma unroll
    for (int i = 0; i < 4; ++i) {
      num0[i] += __uint_as_float(((unsigned)(unsigned short)ov[i]) << 16);
      num1[i] += __uint_as_float(((unsigned)(unsigned short)ov[i + 4]) << 16);
    }
  }
  float inv = 1.f / den;
  f32x4 r0, r1;
#pragma unroll
  for (int i = 0; i < 4; ++i) { r0[i] = num0[i] * inv; r1[i] = num1[i] * inv; }
  float* dst = out + ((size_t)b * 2048 + row) * 128 + c * 8;
  *(f32x4*)dst = r0;
  *(f32x4*)(dst + 4) = r1;
}

// ---------------------------------------------------------------------------
extern "C" void kernel_launch(void* const* d_in, const int* in_sizes, int n_in,
                              void* d_out, int out_size, void* d_ws, size_t ws_size,
                              hipStream_t stream) {
  const float* x  = (const float*)d_in[0];
  const float* Wq = (const float*)d_in[1];
  const float* Wk = (const float*)d_in[2];
  const float* Wv = (const float*)d_in[3];
  float* out = (float*)d_out;

  char* ws = (char*)d_ws;
  __hip_bfloat16* qp  = (__hip_bfloat16*)ws;                        // 4 MB
  __hip_bfloat16* kp  = qp + (size_t)B_ * T_ * 128;                 // 4 MB
  __hip_bfloat16* vpT = kp + (size_t)B_ * T_ * 128;                 // 4 MB
  __hip_bfloat16* po  = (__hip_bfloat16*)(ws + 3 * (size_t)B_ * T_ * 128 * 2); // 18.9 MB
  const size_t nslot = (size_t)8 * UPB;                             // 576
  float* pml = (float*)((char*)po + nslot * 128 * 128 * 2);         // 295 KB

  const size_t need = 3 * (size_t)B_ * T_ * 128 * 2
                    + nslot * 128 * 128 * 2 + nslot * 128 * 4;
  const int chunked = (ws_size >= need) ? 1 : 0;

  proj_kernel<<<dim3(256, 3), 256, 0, stream>>>(x, Wq, Wk, Wv, qp, kp, vpT);
  if (chunked) {
    attn_kernel<<<8 * UPB, 512, 0, stream>>>(qp, kp, vpT, out, po, pml, 1);
    combine_kernel<<<896, 256, 0, stream>>>(po, pml, out);
  } else {
    attn_kernel<<<128, 512, 0, stream>>>(qp, kp, vpT, out, po, pml, 0);
  }
}

// Round 30
// 47.619 us; speedup vs baseline: 1.0524x; 1.0524x over previous
//
#include <hip/hip_runtime.h>
#include <hip/hip_bf16.h>

#define B_ 8
#define T_ 2048
#define D_ 128

typedef __attribute__((ext_vector_type(8))) short short8;
typedef __attribute__((ext_vector_type(4))) float f32x4;

static __device__ __forceinline__ short f2bf(float f) {
  __hip_bfloat16 h = __float2bfloat16(f);
  return *reinterpret_cast<short*>(&h);
}

// scale * log2(e):  (1/sqrt(128)) * 1.4426950408889634
#define SL 0.12754434770570355f

// q-supertile = 128 rows (8 waves x 16). ns(qt) = ceil((qt+1)/2) splits,
// balanced over 4qt+4 KV-tiles (6-8 tiles per block). UPB = sum ns = 72.
// Per-batch partials = 72 x 32 KB = 2.3 MB < 4 MB XCD L2 (R24 lesson).
#define UPB 72

// cumulative blocks before supertile i (ns: 1,1,2,2,3,3,...):
static __device__ __forceinline__ int base16(int i) {
  int m = i >> 1;
  return (i & 1) ? (m + 1) * (m + 1) : m * m + m;
}

// direct global->LDS, 16B per lane (dest = wave-uniform base + lane*16)
static __device__ __forceinline__ void gl_lds16(const void* g, void* l) {
  __builtin_amdgcn_global_load_lds(
      (const __attribute__((address_space(1))) unsigned*)g,
      (__attribute__((address_space(3))) unsigned*)l, 16, 0, 0);
}

// ---------------------------------------------------------------------------
// Kernel 1: projections with FUSED W-transpose. W^T staged per block into
// padded LDS (coalesced f32 pairs -> cvt_pk -> b32 stores). The kp output
// (attn's Q' operand) is PRE-SCALED by SL so attn's softmax is exp2f(sc)
// with no multiply. q,k row-major bf16; v TRANSPOSED [B][D][T].
__global__ __launch_bounds__(256) void proj_kernel(const float* __restrict__ x,
    const float* __restrict__ Wq, const float* __restrict__ Wk,
    const float* __restrict__ Wv,
    __hip_bfloat16* __restrict__ qp, __hip_bfloat16* __restrict__ kp,
    __hip_bfloat16* __restrict__ vpT) {
  const int wv = threadIdx.x >> 6, lane = threadIdx.x & 63;
  const int ar = lane & 15, kg = lane >> 4;
  const int row0 = blockIdx.x * 64 + wv * 16;
  const int b = row0 >> 11, tloc = row0 & 2047;
  const int m = blockIdx.y;

  __shared__ short WTl[128][132];   // W^T[n][k] bf16, +4 pad

  const float* W = (m == 0) ? Wq : (m == 1) ? Wk : Wv;
  // stage W^T: 32 iters, each thread covers (nn, k=2kp..2kp+1), coalesced in nn
#pragma unroll
  for (int it = 0; it < 32; ++it) {
    int idx = it * 256 + threadIdx.x;
    int kp2 = idx >> 7, nn = idx & 127;
    float f0 = W[(2 * kp2) * 128 + nn];
    float f1 = W[(2 * kp2 + 1) * 128 + nn];
    unsigned w;
    asm("v_cvt_pk_bf16_f32 %0, %1, %2" : "=v"(w) : "v"(f0), "v"(f1));
    *(unsigned*)&WTl[nn][2 * kp2] = w;
  }

  short8 a[4];
  {
    const float* px = x + (size_t)(row0 + ar) * 128 + kg * 8;
#pragma unroll
    for (int ks = 0; ks < 4; ++ks) {
      const float* p = px + ks * 32;
      f32x4 x0 = *(const f32x4*)p;
      f32x4 x1 = *(const f32x4*)(p + 4);
      short8 t;
      t[0] = f2bf(x0[0]); t[1] = f2bf(x0[1]); t[2] = f2bf(x0[2]); t[3] = f2bf(x0[3]);
      t[4] = f2bf(x1[0]); t[5] = f2bf(x1[1]); t[6] = f2bf(x1[2]); t[7] = f2bf(x1[3]);
      a[ks] = t;
    }
  }
  __syncthreads();   // W^T staged

  if (m < 2) {
    __hip_bfloat16* outp = (m == 0) ? qp : kp;
    const float osc = (m == 1) ? SL : 1.0f;   // fold softmax scale into kp
#pragma unroll
    for (int nt = 0; nt < 8; ++nt) {
      f32x4 acc = {0.f, 0.f, 0.f, 0.f};
#pragma unroll
      for (int ks = 0; ks < 4; ++ks) {
        short8 bfr = *(const short8*)&WTl[nt * 16 + ar][ks * 32 + kg * 8];
        acc = __builtin_amdgcn_mfma_f32_16x16x32_bf16(a[ks], bfr, acc, 0, 0, 0);
      }
#pragma unroll
      for (int r = 0; r < 4; ++r)
        outp[(size_t)(row0 + kg * 4 + r) * 128 + nt * 16 + ar] = __float2bfloat16(acc[r] * osc);
    }
  } else {
#pragma unroll
    for (int nt = 0; nt < 8; ++nt) {
      f32x4 acc = {0.f, 0.f, 0.f, 0.f};
#pragma unroll
      for (int ks = 0; ks < 4; ++ks) {
        short8 wfr = *(const short8*)&WTl[nt * 16 + ar][ks * 32 + kg * 8];
        acc = __builtin_amdgcn_mfma_f32_16x16x32_bf16(wfr, a[ks], acc, 0, 0, 0);
      }
#pragma unroll
      for (int r = 0; r < 4; ++r)
        vpT[((size_t)b * 128 + nt * 16 + kg * 4 + r) * 2048 + tloc + ar] = __float2bfloat16(acc[r]);
    }
  }
}

// ---------------------------------------------------------------------------
// Kernel 2: causal flash attention (roles swapped: Q'=k_proj(pre-scaled),
// K'=q_proj). 8 waves share one 128-row Q-tile; K/V staged once per block
// into a 4-deep LDS ring via global_load_lds; counted-vmcnt barriers,
// prefetch depth 2 issued BEFORE the wait (verified optimal schedule).
// Fixed-m softmax: P = exp2f(sc) directly (SL folded into kp).
__global__ __launch_bounds__(512, 4) void attn_kernel(const __hip_bfloat16* __restrict__ qp,
    const __hip_bfloat16* __restrict__ kp, const __hip_bfloat16* __restrict__ vpT,
    float* __restrict__ out, __hip_bfloat16* __restrict__ po, float* __restrict__ pml,
    int chunked) {
  const int bid = blockIdx.x;
  const int b = bid & 7;            // batch -> XCD pinning
  const int u = bid >> 3;
  int qt, s, ns;
  if (chunked) {
    int g = 0;
#pragma unroll
    for (int i = 1; i < 16; ++i)
      if (u >= base16(i)) g = i;
    qt = g; s = u - base16(g); ns = (g + 2) >> 1;
  } else {
    qt = u; s = 0; ns = 1;
  }
  const int wv = threadIdx.x >> 6, lane = threadIdx.x & 63;
  const int ar = lane & 15, kg = lane >> 4;

  // KV ring: 4 slots x [frag(16)][lane(64) x 16B]; frags 0-7 = K, 8-15 = V
  __shared__ short KV[4][8192];
  __shared__ short Pl[8][16][52];   // [wave][q(16)][kv(32)+pad]
  short (*Plw)[52] = Pl[wv];

  const int qrow0 = qt * 128 + wv * 16;
  const size_t boff = (size_t)b * T_ * 128;
  const size_t bvoff = (size_t)b * 128 * 2048;

  short8 qf[4];
  {
    const __hip_bfloat16* qb = kp + boff + (size_t)(qrow0 + ar) * 128 + kg * 8;
#pragma unroll
    for (int ks = 0; ks < 4; ++ks) qf[ks] = *(const short8*)(qb + ks * 32);
  }

  f32x4 o[8];
  {
    f32x4 z = {0.f, 0.f, 0.f, 0.f};
#pragma unroll
    for (int i = 0; i < 8; ++i) o[i] = z;
  }
  float lpart = 0.f;   // per-lane: sum of P over this lane's kv set, q = ar

  // balanced KV-tile range over ntile = 4qt+4 tiles
  const int ntile = 4 * qt + 4;
  const int t0 = chunked ? (s * ntile) / ns : 0;
  const int t1 = chunked ? ((s + 1) * ntile) / ns : ntile;
  const int n = t1 - t0;

  // staging sources for this wave (frag fK = wv, frag fV = 8 + wv)
  const __hip_bfloat16* Ksrc0 = qp + boff + (size_t)((wv >> 2) * 16 + ar) * 128 + (wv & 3) * 32 + kg * 8;
  const __hip_bfloat16* Vsrc0 = vpT + bvoff + (size_t)(wv * 16 + ar) * 2048 + kg * 8;

  // prologue: stage tiles t0, t0+1 into ring slots 0,1
  gl_lds16(Ksrc0 + (size_t)t0 * 4096, &KV[0][wv * 512]);
  gl_lds16(Vsrc0 + (size_t)t0 * 32, &KV[0][(8 + wv) * 512]);
  if (n > 1) {
    gl_lds16(Ksrc0 + (size_t)(t0 + 1) * 4096, &KV[1][wv * 512]);
    gl_lds16(Vsrc0 + (size_t)(t0 + 1) * 32, &KV[1][(8 + wv) * 512]);
  }

  for (int i = 0; i < n; ++i) {
    const int t = t0 + i;
    if (i + 2 < n) {   // prefetch tile t+2 into ring slot (i+2)&3
      gl_lds16(Ksrc0 + (size_t)(t + 2) * 4096, &KV[(i + 2) & 3][wv * 512]);
      gl_lds16(Vsrc0 + (size_t)(t + 2) * 32, &KV[(i + 2) & 3][(8 + wv) * 512]);
    }
    // counted wait: FIFO completion guarantees tile t's 2 loads landed
    const int rem = n - 1 - i;
    if (rem >= 2)      asm volatile("s_waitcnt vmcnt(4)" ::: "memory");
    else if (rem == 1) asm volatile("s_waitcnt vmcnt(2)" ::: "memory");
    else               asm volatile("s_waitcnt vmcnt(0)" ::: "memory");
    __builtin_amdgcn_s_barrier();
    asm volatile("" ::: "memory");

    const short* buf = KV[i & 3];
    const int rel = qrow0 - t * 32;   // wave-uniform; >=31 -> no mask fires

    // --- QK: S^T = K Q'^T; lane(kg,ar) reg r = S^T[kv=nt*16+kg*4+r][q=ar]
    f32x4 sc[2];
#pragma unroll
    for (int nt = 0; nt < 2; ++nt) {
      f32x4 acc = {0.f, 0.f, 0.f, 0.f};
#pragma unroll
      for (int ks = 0; ks < 4; ++ks) {
        short8 kf = *(const short8*)&buf[(nt * 4 + ks) * 512 + lane * 8];
        acc = __builtin_amdgcn_mfma_f32_16x16x32_bf16(kf, qf[ks], acc, 0, 0, 0);
      }
      sc[nt] = acc;
    }

    // --- P = exp2f(sc) (SL pre-folded); pack 4 bf16 -> one b64 LDS store ---
    if (rel >= 31) {
#pragma unroll
      for (int nt = 0; nt < 2; ++nt) {
        float p0 = exp2f(sc[nt][0]), p1 = exp2f(sc[nt][1]);
        float p2 = exp2f(sc[nt][2]), p3 = exp2f(sc[nt][3]);
        lpart += (p0 + p1) + (p2 + p3);
        unsigned w0, w1;
        asm("v_cvt_pk_bf16_f32 %0, %1, %2" : "=v"(w0) : "v"(p0), "v"(p1));
        asm("v_cvt_pk_bf16_f32 %0, %1, %2" : "=v"(w1) : "v"(p2), "v"(p3));
        *(unsigned long long*)&Plw[ar][nt * 16 + kg * 4] =
            ((unsigned long long)w1 << 32) | (unsigned long long)w0;
      }
    } else {
#pragma unroll
      for (int nt = 0; nt < 2; ++nt) {
        float p[4];
#pragma unroll
        for (int r = 0; r < 4; ++r) {
          float v = sc[nt][r];
          if (nt * 16 + kg * 4 + r - rel > ar) v = -3.0e38f;   // kv > q
          p[r] = exp2f(v);
          lpart += p[r];
        }
        unsigned w0, w1;
        asm("v_cvt_pk_bf16_f32 %0, %1, %2" : "=v"(w0) : "v"(p[0]), "v"(p[1]));
        asm("v_cvt_pk_bf16_f32 %0, %1, %2" : "=v"(w1) : "v"(p[2]), "v"(p[3]));
        *(unsigned long long*)&Plw[ar][nt * 16 + kg * 4] =
            ((unsigned long long)w1 << 32) | (unsigned long long)w0;
      }
    }

    // --- PV: O += P @ V (A = P rows from LDS, B = V^T frags) ---
    short8 pa = *(const short8*)&Plw[ar][kg * 8];
#pragma unroll
    for (int n8 = 0; n8 < 8; ++n8) {
      short8 vf = *(const short8*)&buf[(8 + n8) * 512 + lane * 8];
      o[n8] = __builtin_amdgcn_mfma_f32_16x16x32_bf16(pa, vf, o[n8], 0, 0, 0);
    }
  }

  // epilogue: l[q=ar] = sum over the 4 kg-groups; then fetch l for q=kg*4+r
  lpart += __shfl_xor(lpart, 16);
  lpart += __shfl_xor(lpart, 32);
  float lq[4];
#pragma unroll
  for (int r = 0; r < 4; ++r)
    lq[r] = __shfl(lpart, kg * 4 + r);

  if (ns == 1) {
#pragma unroll
    for (int r = 0; r < 4; ++r) lq[r] = 1.f / lq[r];
#pragma unroll
    for (int n8 = 0; n8 < 8; ++n8)
#pragma unroll
      for (int r = 0; r < 4; ++r)
        out[boff + (size_t)(qrow0 + kg * 4 + r) * 128 + n8 * 16 + ar] = o[n8][r] * lq[r];
  } else {
    // partial write (unnormalized bf16 o + f32 l)
    const int slot = b * UPB + u;
    __hip_bfloat16* pb = po + (size_t)slot * 128 * 128;
#pragma unroll
    for (int n8 = 0; n8 < 8; ++n8)
#pragma unroll
      for (int r = 0; r < 4; ++r)
        pb[(wv * 16 + kg * 4 + r) * 128 + n8 * 16 + ar] = __float2bfloat16(o[n8][r]);
    if (ar == 0) {
#pragma unroll
      for (int r = 0; r < 4; ++r)
        pml[slot * 128 + wv * 16 + kg * 4 + r] = lq[r];
    }
  }
}

// ---------------------------------------------------------------------------
// Kernel 3: merge splits for supertiles with ns>=2 (qt>=2: rows 256..2047).
// Vectorized: each thread handles 8 floats (one 16B bf16 load per split).
// thread = (b, row, 8-elem d chunk); grid = 8*1792*16/256 = 896 blocks.
__global__ __launch_bounds__(256) void combine_kernel(const __hip_bfloat16* __restrict__ po,
    const float* __restrict__ pml, float* __restrict__ out) {
  const int g0 = blockIdx.x * 256 + threadIdx.x;
  const int c = g0 & 15;                 // 8-float chunk index
  const int rowm = (g0 >> 4) % 1792;
  const int b = g0 / (1792 * 16);
  const int row = 256 + rowm;
  const int qt = row >> 7;
  const int ns = (qt + 2) >> 1;
  const int rowin = row & 127;
  const int slot0 = b * UPB + base16(qt);

  f32x4 num0 = {0.f, 0.f, 0.f, 0.f};
  f32x4 num1 = {0.f, 0.f, 0.f, 0.f};
  float den = 0.f;
  for (int s = 0; s < ns; ++s) {
    den += pml[(slot0 + s) * 128 + rowin];
    short8 ov = *(const short8*)(po + (size_t)(slot0 + s) * 128 * 128 + rowin * 128 + c * 8);
#pragma unroll
    for (int i = 0; i < 4; ++i) {
      num0[i] += __uint_as_float(((unsigned)(unsigned short)ov[i]) << 16);
      num1[i] += __uint_as_float(((unsigned)(unsigned short)ov[i + 4]) << 16);
    }
  }
  float inv = 1.f / den;
  f32x4 r0, r1;
#pragma unroll
  for (int i = 0; i < 4; ++i) { r0[i] = num0[i] * inv; r1[i] = num1[i] * inv; }
  float* dst = out + ((size_t)b * 2048 + row) * 128 + c * 8;
  *(f32x4*)dst = r0;
  *(f32x4*)(dst + 4) = r1;
}

// ---------------------------------------------------------------------------
extern "C" void kernel_launch(void* const* d_in, const int* in_sizes, int n_in,
                              void* d_out, int out_size, void* d_ws, size_t ws_size,
                              hipStream_t stream) {
  const float* x  = (const float*)d_in[0];
  const float* Wq = (const float*)d_in[1];
  const float* Wk = (const float*)d_in[2];
  const float* Wv = (const float*)d_in[3];
  float* out = (float*)d_out;

  char* ws = (char*)d_ws;
  __hip_bfloat16* qp  = (__hip_bfloat16*)ws;                        // 4 MB
  __hip_bfloat16* kp  = qp + (size_t)B_ * T_ * 128;                 // 4 MB
  __hip_bfloat16* vpT = kp + (size_t)B_ * T_ * 128;                 // 4 MB
  __hip_bfloat16* po  = (__hip_bfloat16*)(ws + 3 * (size_t)B_ * T_ * 128 * 2); // 18.9 MB
  const size_t nslot = (size_t)8 * UPB;                             // 576
  float* pml = (float*)((char*)po + nslot * 128 * 128 * 2);         // 295 KB

  const size_t need = 3 * (size_t)B_ * T_ * 128 * 2
                    + nslot * 128 * 128 * 2 + nslot * 128 * 4;
  const int chunked = (ws_size >= need) ? 1 : 0;

  proj_kernel<<<dim3(256, 3), 256, 0, stream>>>(x, Wq, Wk, Wv, qp, kp, vpT);
  if (chunked) {
    attn_kernel<<<8 * UPB, 512, 0, stream>>>(qp, kp, vpT, out, po, pml, 1);
    combine_kernel<<<896, 256, 0, stream>>>(po, pml, out);
  } else {
    attn_kernel<<<128, 512, 0, stream>>>(qp, kp, vpT, out, po, pml, 0);
  }
}